// Round 7
// baseline (27944.077 us; speedup 1.0000x reference)
//
#include <hip/hip_runtime.h>
#include <hip/hip_bf16.h>
#include <math.h>

#define NB 32
#define NKS 2048
#define NKG 512
#define NH 512
#define NH3 1536
#define NV 32000
#define NSTEPS 64
#define NTILES 40            // per b: 32 sent + 8 graph (64 keys each)

typedef unsigned long long u64;
typedef unsigned int u32;
typedef unsigned short u16;
typedef __attribute__((ext_vector_type(8))) short short8;
typedef __attribute__((ext_vector_type(4))) float f32x4;

__device__ __forceinline__ float bfu(u32 u){ return __uint_as_float(u << 16); }
__device__ __forceinline__ u16 f2bf(float f){
  u32 b = __float_as_uint(f);
  return (u16)((b + 0x7FFFu + ((b>>16)&1u)) >> 16);
}

// ---- one-time: pack W_out into bf16 MFMA B-fragment order (validated r4) ----
__global__ void k_packw(const float* __restrict__ W, u16* __restrict__ wp){
  long t = (long)blockIdx.x*256 + threadIdx.x;   // 6,144,000 total
  int lane = (int)(t & 63);
  long g = t >> 6;
  int kc = (int)(g % 48);
  int v16 = (int)(g / 48);
  int v = v16*16 + (lane&15);
  int k0 = kc*32 + (lane>>4)*8;
  const float4* src = (const float4*)(W + (size_t)v*NH3 + k0);
  float4 a = src[0], b = src[1];
  float vals[8] = {a.x,a.y,a.z,a.w,b.x,b.y,b.z,b.w};
  u16 o[8];
  #pragma unroll
  for (int i=0;i<8;i++) o[i] = f2bf(vals[i]);
  uint4 out;
  out.x = (u32)o[0] | ((u32)o[1]<<16);
  out.y = (u32)o[2] | ((u32)o[3]<<16);
  out.z = (u32)o[4] | ((u32)o[5]<<16);
  out.w = (u32)o[6] | ((u32)o[7]<<16);
  ((uint4*)wp)[t] = out;
}

// ---- once per launch: hdT[k][b] = enc, embT[k][b] = emb[BOS] ---------------
__global__ void k_init(const float* __restrict__ enc, const float* __restrict__ emb,
                       double* __restrict__ hdT, double* __restrict__ embT){
  int i = blockIdx.x*256 + threadIdx.x;   // 64x256 = 16384 = NB*NH
  int b = i>>9, k = i&511;
  hdT[k*NB + b]  = (double)enc[i];
  embT[k*NB + b] = (double)emb[NH + k];   // BOS token = 1
}

// ---- per step (fp64): q = Wa@h, gx = Wih@emb+b, gh = Whh@h+b (validated r6) -
__global__ __launch_bounds__(256) void k_gates(
    const double* __restrict__ hdT, const double* __restrict__ embT,
    const float* __restrict__ Wa, const float* __restrict__ Wih,
    const float* __restrict__ Whh,
    const float* __restrict__ bih, const float* __restrict__ bhh,
    double* __restrict__ qd, double* __restrict__ gxd, double* __restrict__ ghd)
{
  __shared__ float Wlds[8*512];            // 16 KB
  __shared__ double xls[64*NB];            // 16 KB per k-chunk
  int blk = blockIdx.x, tid = threadIdx.x;
  const float* Wseg; const double* xg; int row0;
  if (blk < 64){ Wseg = Wa; row0 = blk*8; xg = hdT; }
  else if (blk < 256){ Wseg = Wih; row0 = (blk-64)*8; xg = embT; }
  else { Wseg = Whh; row0 = (blk-256)*8; xg = hdT; }
  { const float4* src = (const float4*)(Wseg + (size_t)row0*NH);
    float4* d4 = (float4*)Wlds;
    for (int j=tid; j<1024; j+=256) d4[j] = src[j]; }
  int ol = tid>>5, b = tid&31;
  double acc = 0.0;
  for (int kc=0; kc<8; kc++){
    __syncthreads();
    for (int j=tid; j<64*NB; j+=256) xls[j] = xg[(size_t)kc*64*NB + j];
    __syncthreads();
    #pragma unroll 16
    for (int kk=0; kk<64; kk++)
      acc += (double)Wlds[ol*512 + kc*64 + kk] * xls[kk*NB + b];
  }
  if (blk < 64){
    qd[(size_t)b*NH + row0 + ol] = acc;
  } else if (blk < 256){
    int o = row0 + ol;
    gxd[(size_t)b*NH3 + o] = acc + (double)bih[o];
  } else {
    int o = row0 + ol;
    ghd[(size_t)b*NH3 + o] = acc + (double)bhh[o];
  }
}

// ---- per step: fused exact fp64 attention, 64-key tiles, LDS-staged once ----
// grid 1280 x 512 thr: blk<1024 sent (32 tiles/b), else graph (8 tiles/b)
__global__ __launch_bounds__(512) void k_att(
  const float* __restrict__ sf, const float* __restrict__ gf,
  const double* __restrict__ qd,
  double* __restrict__ pc, double* __restrict__ pden, double* __restrict__ ptm)
{
  extern __shared__ float rows[];          // 64 rows x 512 f32 = 128 KB
  __shared__ double sc[64];
  __shared__ double wexp[64];
  __shared__ double smax_s;
  int blk = blockIdx.x, tid = threadIdx.x;
  int b, tile, K, tslot; const float* src;
  if (blk < 1024){ b = blk>>5; tile = blk&31; K = NKS; src = sf; tslot = b*NTILES + tile; }
  else { int bb = blk-1024; b = bb>>3; tile = bb&7; K = NKG; src = gf; tslot = b*NTILES + 32 + tile; }
  int lane = tid&63, wv = tid>>6;
  // stage 64 rows (128 KB) into LDS, coalesced
  { const float4* gsrc = (const float4*)(src + ((size_t)b*K + (size_t)tile*64)*NH);
    float4* d4 = (float4*)rows;
    for (int j = tid; j < 64*128; j += 512) d4[j] = gsrc[j]; }
  double qv[8];
  { const double* qb = qd + (size_t)b*NH + lane*8;
    #pragma unroll
    for (int j=0;j<8;j++) qv[j] = qb[j]; }
  __syncthreads();
  // scores: wave wv owns rows wv*8 .. wv*8+7, processed in pairs
  for (int r = wv*8; r < wv*8+8; r += 2){
    const float4* rA = (const float4*)(rows + (size_t)r*NH) + lane*2;
    const float4* rB = (const float4*)(rows + (size_t)(r+1)*NH) + lane*2;
    float4 a0 = rA[0], a1 = rA[1], c0f = rB[0], c1f = rB[1];
    double sA = (double)a0.x*qv[0]+(double)a0.y*qv[1]+(double)a0.z*qv[2]+(double)a0.w*qv[3]
              + (double)a1.x*qv[4]+(double)a1.y*qv[5]+(double)a1.z*qv[6]+(double)a1.w*qv[7];
    double sB = (double)c0f.x*qv[0]+(double)c0f.y*qv[1]+(double)c0f.z*qv[2]+(double)c0f.w*qv[3]
              + (double)c1f.x*qv[4]+(double)c1f.y*qv[5]+(double)c1f.z*qv[6]+(double)c1f.w*qv[7];
    #pragma unroll
    for (int off=32; off>=1; off>>=1){ sA += __shfl_xor(sA, off); sB += __shfl_xor(sB, off); }
    if (lane==0){ sc[r] = sA; sc[r+1] = sB; }
  }
  __syncthreads();
  if (tid < 64){
    double v = sc[tid];
    #pragma unroll
    for (int off=32; off>=1; off>>=1) v = fmax(v, __shfl_xor(v, off));
    if (tid==0) smax_s = v;
  }
  __syncthreads();
  double m = smax_s;
  if (tid < 64){
    double w = exp(sc[tid] - m);
    wexp[tid] = w;
    #pragma unroll
    for (int off=32; off>=1; off>>=1) w += __shfl_xor(w, off);
    if (tid==0){ pden[tslot] = w; ptm[tslot] = m; }
  }
  __syncthreads();
  // weighted values from LDS: thread owns dim tid
  double c = 0.0;
  #pragma unroll 8
  for (int i=0;i<64;i++)
    c += wexp[i] * (double)rows[(size_t)i*NH + tid];
  pc[(size_t)tslot*NH + tid] = c;
}

// ---- per step (fp64): merge 40 tiles, GRU, x + hdT + split-bf16 frags -------
__global__ __launch_bounds__(256) void k_comb(
  const double* __restrict__ pc, const double* __restrict__ pden,
  const double* __restrict__ ptm,
  const double* __restrict__ gxd, const double* __restrict__ ghd,
  double* __restrict__ hdT, double* __restrict__ xd, u16* __restrict__ apack)
{
  int b = blockIdx.x, half = blockIdx.y, tid = threadIdx.x;
  int i = half*256 + tid;
  __shared__ double scale[NTILES];
  __shared__ double dent[2];
  __shared__ double mshare[2];
  if (tid==0){
    double ms = -1e300, mg = -1e300;
    for (int t=0;t<32;t++)       ms = fmax(ms, ptm[b*NTILES+t]);
    for (int t=32;t<NTILES;t++)  mg = fmax(mg, ptm[b*NTILES+t]);
    mshare[0] = ms; mshare[1] = mg;
  }
  __syncthreads();
  if (tid < NTILES){
    double mm = (tid<32) ? mshare[0] : mshare[1];
    scale[tid] = exp(ptm[b*NTILES+tid] - mm);
  }
  __syncthreads();
  if (tid==0){
    double ds = 0.0, dg = 0.0;
    for (int t=0;t<32;t++)      ds += pden[b*NTILES+t]*scale[t];
    for (int t=32;t<NTILES;t++) dg += pden[b*NTILES+t]*scale[t];
    dent[0] = ds; dent[1] = dg;
  }
  __syncthreads();
  double cs = 0.0, cg = 0.0;
  for (int t=0;t<32;t++)      cs += pc[(size_t)(b*NTILES+t)*NH + i]*scale[t];
  for (int t=32;t<NTILES;t++) cg += pc[(size_t)(b*NTILES+t)*NH + i]*scale[t];
  cs /= dent[0]; cg /= dent[1];
  double xr = gxd[(size_t)b*NH3 + i],        hr = ghd[(size_t)b*NH3 + i];
  double xz = gxd[(size_t)b*NH3 + NH + i],   hz = ghd[(size_t)b*NH3 + NH + i];
  double xn = gxd[(size_t)b*NH3 + 2*NH + i], hn = ghd[(size_t)b*NH3 + 2*NH + i];
  double r = 1.0/(1.0+exp(-(xr+hr)));
  double z = 1.0/(1.0+exp(-(xz+hz)));
  double nn = tanh(xn + r*hn);
  double hold = hdT[(size_t)i*NB + b];
  double hnew = (1.0 - z)*nn + z*hold;
  hdT[(size_t)i*NB + b] = hnew;
  int mt = b>>4, row = b&15;
  double vals[3] = {hnew, cg, cs};
  #pragma unroll
  for (int c=0;c<3;c++){
    int col = c*NH + i;
    xd[(size_t)b*NH3 + col] = vals[c];
    int kc = col>>5, kg = (col&31)>>3, j = col&7;
    int lane = row + 16*kg;
    size_t base = ((size_t)(mt*48+kc)*64 + lane)*8 + j;
    float xf = (float)vals[c];
    u16 hi = f2bf(xf);
    float rem = (float)(vals[c] - (double)bfu((u32)hi));
    apack[base] = hi;
    apack[base + (size_t)2*48*64*8] = f2bf(rem);   // lo block after hi block
  }
}

// --------- per step: logits via split-bf16 MFMA; store-only (no atomics) -----
__global__ __launch_bounds__(256) void k_logv(
  const u16* __restrict__ apack, const u16* __restrict__ wpack,
  const float* __restrict__ bout, float* __restrict__ dst)
{
  int tid = threadIdx.x;
  int wv = tid>>6, lane = tid&63;
  int v16 = blockIdx.x*4 + wv;                    // 500 blocks -> 2000 tiles
  const short8* bp = (const short8*)wpack + (size_t)v16*48*64 + lane;
  const short8* ap = (const short8*)apack + lane;
  f32x4 acc0 = {0.f,0.f,0.f,0.f}, acc1 = {0.f,0.f,0.f,0.f};
  #pragma unroll 4
  for (int kc=0; kc<48; kc++){
    short8 bf = bp[(size_t)kc*64];
    short8 a0h = ap[(size_t)kc*64];
    short8 a1h = ap[(size_t)(48+kc)*64];
    short8 a0l = ap[(size_t)(96+kc)*64];
    short8 a1l = ap[(size_t)(144+kc)*64];
    acc0 = __builtin_amdgcn_mfma_f32_16x16x32_bf16(a0h, bf, acc0, 0, 0, 0);
    acc0 = __builtin_amdgcn_mfma_f32_16x16x32_bf16(a0l, bf, acc0, 0, 0, 0);
    acc1 = __builtin_amdgcn_mfma_f32_16x16x32_bf16(a1h, bf, acc1, 0, 0, 0);
    acc1 = __builtin_amdgcn_mfma_f32_16x16x32_bf16(a1l, bf, acc1, 0, 0, 0);
  }
  int col = v16*16 + (lane&15);
  float bias = bout[col];
  int r0 = (lane>>4)*4;
  #pragma unroll
  for (int r=0;r<4;r++){
    int b0 = r0 + r;
    dst[(size_t)b0*NV + col] = acc0[r] + bias;
    dst[(size_t)(16+b0)*NV + col] = acc1[r] + bias;
  }
}

// ---- per step: self-scanned max, fp64 argmax refinement, embT for t+1 -------
__global__ __launch_bounds__(256) void k_refine(
  float* __restrict__ logits, const double* __restrict__ xd,
  const float* __restrict__ Wout, const float* __restrict__ bout,
  const float* __restrict__ emb, double* __restrict__ embT)
{
  int b = blockIdx.x, tid = threadIdx.x;
  __shared__ double xs[NH3];          // 12 KB
  for (int i=tid;i<NH3;i+=256) xs[i] = xd[(size_t)b*NH3 + i];
  const float4* lg = (const float4*)(logits + (size_t)b*NV);
  // pass 0: bulk max via scan (replaces global atomics)
  float mx = -1e30f;
  for (int i=tid; i<NV/4; i+=256){
    float4 v = lg[i];
    mx = fmaxf(mx, fmaxf(fmaxf(v.x,v.y), fmaxf(v.z,v.w)));
  }
  __shared__ float mred[256];
  mred[tid] = mx; __syncthreads();
  for (int s=128;s>0;s>>=1){ if (tid<s) mred[tid] = fmaxf(mred[tid], mred[tid+s]); __syncthreads(); }
  float maxv = mred[0];
  __shared__ int cnt;
  __shared__ int cand[2048];          // 8 KB
  __shared__ double cval[2048];       // 16 KB
  float margin = 1.0f;
  for (int attempt=0; attempt<2; attempt++){
    if (tid==0) cnt = 0;
    __syncthreads();
    float thr = maxv - margin;
    for (int i=tid; i<NV/4; i+=256){
      float4 v = lg[i];
      if (v.x>thr){ int p=atomicAdd(&cnt,1); if(p<2048) cand[p]=i*4+0; }
      if (v.y>thr){ int p=atomicAdd(&cnt,1); if(p<2048) cand[p]=i*4+1; }
      if (v.z>thr){ int p=atomicAdd(&cnt,1); if(p<2048) cand[p]=i*4+2; }
      if (v.w>thr){ int p=atomicAdd(&cnt,1); if(p<2048) cand[p]=i*4+3; }
    }
    __syncthreads();
    if (cnt <= 2048) break;
    margin = 0.125f;                  // bulk err << 0.125, true argmax still included
    __syncthreads();
  }
  int n = min(cnt, 2048);
  int wv = tid>>6, lane = tid&63;
  for (int c=wv; c<n; c+=4){
    int v = cand[c];
    const float4* wr = (const float4*)(Wout + (size_t)v*NH3);
    double a = 0.0;
    #pragma unroll
    for (int i=0;i<6;i++){
      int e = lane + 64*i;
      float4 w4 = wr[e];
      a += (double)w4.x*xs[e*4+0] + (double)w4.y*xs[e*4+1]
         + (double)w4.z*xs[e*4+2] + (double)w4.w*xs[e*4+3];
    }
    #pragma unroll
    for (int off=32; off>=1; off>>=1) a += __shfl_xor(a, off);
    if (lane==0){
      double av = a + (double)bout[v];
      cval[c] = av;
      logits[(size_t)b*NV + v] = (float)av;
    }
  }
  __syncthreads();
  __shared__ int bidx;
  if (tid==0){
    double bv = -1e300; int bi = 0x7fffffff;
    for (int c=0;c<n;c++){
      if (cval[c] > bv || (cval[c] == bv && cand[c] < bi)){ bv = cval[c]; bi = cand[c]; }
    }
    bidx = bi;
  }
  __syncthreads();
  int bi = bidx;
  for (int k=tid; k<NH; k+=256)
    embT[(size_t)k*NB + b] = (double)emb[(size_t)bi*NH + k];
}

// -------- fp32 fallback bulk logits (used only if ws can't hold packed W) ----
__global__ __launch_bounds__(256) void k_logits(
  const double* __restrict__ xd, const float* __restrict__ Wout,
  const float* __restrict__ bout, float* __restrict__ dst)
{
  __shared__ float4 xs4[NB*128];
  int tid = threadIdx.x;
  int bg = tid>>6, lane = tid&63;
  int vbase = blockIdx.x*128;
  int v0 = vbase + lane, v1 = vbase + 64 + lane;
  float acc0[8] = {0.f,0.f,0.f,0.f,0.f,0.f,0.f,0.f};
  float acc1[8] = {0.f,0.f,0.f,0.f,0.f,0.f,0.f,0.f};
  for (int c=0;c<3;c++){
    int kb = c*NH;
    for (int i=tid;i<NB*128;i+=256){
      int b=i>>7, kk=i&127;
      float4 t;
      t.x = (float)xd[(size_t)b*NH3 + kb + kk*4+0];
      t.y = (float)xd[(size_t)b*NH3 + kb + kk*4+1];
      t.z = (float)xd[(size_t)b*NH3 + kb + kk*4+2];
      t.w = (float)xd[(size_t)b*NH3 + kb + kk*4+3];
      xs4[i] = t;
    }
    __syncthreads();
    const float4* w0 = (const float4*)(Wout + (size_t)v0*NH3 + kb);
    const float4* w1 = (const float4*)(Wout + (size_t)v1*NH3 + kb);
    for (int k4=0;k4<128;k4++){
      float4 a = w0[k4], bb = w1[k4];
      #pragma unroll
      for (int j=0;j<8;j++){
        float4 xv = xs4[(bg*8+j)*128 + k4];
        acc0[j] += a.x*xv.x;  acc0[j] += a.y*xv.y;  acc0[j] += a.z*xv.z;  acc0[j] += a.w*xv.w;
        acc1[j] += bb.x*xv.x; acc1[j] += bb.y*xv.y; acc1[j] += bb.z*xv.z; acc1[j] += bb.w*xv.w;
      }
    }
    __syncthreads();
  }
  float b0 = bout[v0], b1 = bout[v1];
  #pragma unroll
  for (int j=0;j<8;j++){
    int b = bg*8+j;
    dst[(size_t)b*NV + v0] = acc0[j]+b0;
    dst[(size_t)b*NV + v1] = acc1[j]+b1;
  }
}

extern "C" void kernel_launch(void* const* d_in, const int* in_sizes, int n_in,
                              void* d_out, int out_size, void* d_ws, size_t ws_size,
                              hipStream_t stream) {
  const float* sent  = (const float*)d_in[0];
  const float* graph = (const float*)d_in[1];
  const float* enc   = (const float*)d_in[2];
  const float* Wa    = (const float*)d_in[3];
  const float* emb   = (const float*)d_in[4];
  const float* Wih   = (const float*)d_in[5];
  const float* Whh   = (const float*)d_in[6];
  const float* bih   = (const float*)d_in[7];
  const float* bhh   = (const float*)d_in[8];
  const float* Wout  = (const float*)d_in[9];
  const float* bout  = (const float*)d_in[10];
  float* out = (float*)d_out;

  char* wsb = (char*)d_ws;
  size_t off = 0;
  auto allocd = [&](size_t n)->double*{ double* p = (double*)(wsb + off); off += n*8; return p; };
  double* hdT = allocd(NB*NH);
  double* embT= allocd(NB*NH);
  double* qd  = allocd(NB*NH);
  double* gxd = allocd((size_t)NB*NH3);
  double* ghd = allocd((size_t)NB*NH3);
  double* xd  = allocd((size_t)NB*NH3);
  double* pc  = allocd((size_t)NB*NTILES*NH);
  double* pden= allocd(NB*NTILES);
  double* ptm = allocd(NB*NTILES);
  u16* apack = (u16*)(wsb + off); off += (size_t)4*48*64*8*2;  // hi+lo blocks

  size_t wpoff = (off + 255) & ~(size_t)255;
  const size_t WPBYTES = (size_t)2000*48*64*16;   // 98,304,000
  int usew = (ws_size >= wpoff + WPBYTES) ? 1 : 0;
  u16* wpack = (u16*)(wsb + wpoff);

  if (usew) k_packw<<<dim3(24000), dim3(256), 0, stream>>>(Wout, wpack);
  k_init<<<dim3(64), dim3(256), 0, stream>>>(enc, emb, hdT, embT);

  const u32 attLds = 64*512*4;   // 128 KB dynamic LDS

  for (int t=0; t<NSTEPS; t++){
    k_gates<<<dim3(448), dim3(256), 0, stream>>>(hdT, embT, Wa, Wih, Whh, bih, bhh,
                                                 qd, gxd, ghd);
    k_att<<<dim3(1280), dim3(512), attLds, stream>>>(sent, graph, qd, pc, pden, ptm);
    k_comb<<<dim3(32,2), dim3(256), 0, stream>>>(pc, pden, ptm, gxd, ghd, hdT, xd, apack);
    float* dst = out + (size_t)t*NB*NV;
    if (usew){
      k_logv<<<dim3(500), dim3(256), 0, stream>>>(apack, wpack, bout, dst);
    } else {
      k_logits<<<dim3(250), dim3(256), 0, stream>>>(xd, Wout, bout, dst);
    }
    k_refine<<<dim3(32), dim3(256), 0, stream>>>(dst, xd, Wout, bout, emb, embT);
  }
}